// Round 20
// baseline (265.866 us; speedup 1.0000x reference)
//
#include <hip/hip_runtime.h>
#include <hip/hip_bf16.h>

typedef __attribute__((ext_vector_type(8))) short bf16x8;
typedef __attribute__((ext_vector_type(4))) short bf16x4s;
typedef __attribute__((ext_vector_type(4))) float f32x4;
typedef __attribute__((ext_vector_type(2))) unsigned int u32x2;
typedef unsigned int u32;

#define DIM 2048
#define NH 32
#define NKV 8
#define HD 64
#define BB 2
#define SS 2048
#define MROWS (BB*SS)     // 4096
#define NQKV 3072         // 2048 q + 512 k + 512 v columns
#define KDIM 2048
#define L2E 1.44269504f

__device__ __forceinline__ short f2bf(float f){
  u32 u = __float_as_uint(f);
  u32 r = u + 0x7fffu + ((u >> 16) & 1u);   // RNE
  return (short)(r >> 16);
}
__device__ __forceinline__ float bf2f(short s){
  return __uint_as_float(((u32)(unsigned short)s) << 16);
}

// async global->LDS, 16B per lane; dest must be wave-uniform base (+lane*16 implicit)
__device__ __forceinline__ void gload16(const void* g, void* l){
  __builtin_amdgcn_global_load_lds((const __attribute__((address_space(1))) u32*)g,
                                   (__attribute__((address_space(3))) u32*)l, 16, 0, 0);
}

// ---------------- fused fp32->bf16 convert of all 5 inputs + RoPE tables (1 launch) ----------------
__global__ __launch_bounds__(256) void cvt_all_kernel(const float* __restrict__ x,
                                                      const float* __restrict__ wq,
                                                      const float* __restrict__ wk,
                                                      const float* __restrict__ wv,
                                                      const float* __restrict__ wo,
                                                      short* __restrict__ xb,
                                                      short* __restrict__ wqkvb,
                                                      short* __restrict__ wob,
                                                      float* __restrict__ cosT,
                                                      float* __restrict__ sinT){
  int bid = blockIdx.x;
  if (bid >= 18432){   // RoPE tables: 256 blocks, idx over S*32
    int idx = (bid-18432)*256 + threadIdx.x;
    int s = idx >> 5, i = idx & 31;
    float inv = powf(10000.f, -(float)i * (1.f/32.f));
    float f = (float)s * inv;
    cosT[idx] = cosf(f);
    sinT[idx] = sinf(f);
    return;
  }
  int i = bid*256 + threadIdx.x;
  const float* src; short* dst; int off;
  if      (bid <  8192){ src = x;  dst = xb;              off = 0; }
  else if (bid < 12288){ src = wq; dst = wqkvb;           off = 2097152; }
  else if (bid < 13312){ src = wk; dst = wqkvb+2048*2048; off = 3145728; }
  else if (bid < 14336){ src = wv; dst = wqkvb+2560*2048; off = 3407872; }
  else                 { src = wo; dst = wob;             off = 3670016; }
  int j = i - off;
  f32x4 v = ((const f32x4*)src)[j];
  bf16x4s o;
  #pragma unroll
  for (int t=0;t<4;++t) o[t] = f2bf(v[t]);
  ((bf16x4s*)dst)[j] = o;
}

// ---------------- V^T materialization: Vtg[b][hkv][d=64][S] = V[b][s][hkv][d] ----------------
__global__ __launch_bounds__(256) void vT_kernel(const short* __restrict__ qkv,
                                                 short* __restrict__ Vtg){
  __shared__ short T[64*72];
  const int tid = threadIdx.x;
  const int s0 = blockIdx.x*64, hkv = blockIdx.y, b = blockIdx.z;
  const short* vbase = qkv + (size_t)b*SS*NQKV + DIM + NKV*HD + hkv*HD;
  #pragma unroll
  for (int cc=0; cc<2; ++cc){
    int c = tid + cc*256;
    int s = c >> 3, dc = c & 7;
    bf16x8 v = *(const bf16x8*)(vbase + (size_t)(s0+s)*NQKV + dc*8);
    #pragma unroll
    for (int i=0;i<8;++i) T[(dc*8+i)*72 + s] = v[i];
  }
  __syncthreads();
  short* obase = Vtg + ((size_t)(b*NKV + hkv)*64)*SS;
  #pragma unroll
  for (int cc=0; cc<2; ++cc){
    int c = tid + cc*256;
    int d = c >> 3, sc = c & 7;
    *(bf16x8*)(obase + (size_t)d*SS + s0 + sc*8) = *(const bf16x8*)&T[d*72 + sc*8];
  }
}

// ---------------- GEMM (bf16 out, optional fused RoPE): BK=64, XOR swizzle, XCD swizzle ----------------
__global__ __launch_bounds__(256) void gemm_bt_kernel(const short* __restrict__ A,
                                                      const short* __restrict__ Bm,
                                                      short* __restrict__ C,
                                                      int ldc, int K,
                                                      const float* __restrict__ cosT,
                                                      const float* __restrict__ sinT,
                                                      int rope){
  __shared__ short As[128*64];   // 16KB, rows 128B, chunk-swizzled
  __shared__ short Bs[128*64];
  const int tid = threadIdx.x;
  const int wave = tid >> 6, lane = tid & 63;
  const int g = lane >> 4, r16 = lane & 15;
  // XCD-aware chunked swizzle (T1); valid since gridDim.x*gridDim.y % 8 == 0
  const int nx = gridDim.x, nwg = nx*gridDim.y;
  const int flat = blockIdx.y*nx + blockIdx.x;
  const int swz = (flat & 7)*(nwg >> 3) + (flat >> 3);
  const int m0 = (swz / nx) * 128, n0 = (swz % nx) * 128;
  const int wr = wave >> 1, wc = wave & 1;
  f32x4 acc[4][4] = {};
  for (int k0 = 0; k0 < K; k0 += 64){
    #pragma unroll
    for (int it = 0; it < 4; ++it){
      int ch = it*256 + wave*64 + lane;       // chunk 0..1023
      int row = ch >> 3, kc = ch & 7;
      int skc = kc ^ (row & 7);               // pre-swizzle SOURCE (rule #21)
      gload16(A  + (size_t)(m0+row)*K + k0 + skc*8, (char*)As + it*4096 + wave*1024);
      gload16(Bm + (size_t)(n0+row)*K + k0 + skc*8, (char*)Bs + it*4096 + wave*1024);
    }
    __syncthreads();
    #pragma unroll
    for (int kk=0; kk<2; ++kk){
      bf16x8 a[4], b[4];
      #pragma unroll
      for (int i=0;i<4;++i){
        int Ra = wr*64 + i*16 + r16;
        a[i] = *(const bf16x8*)((const char*)As + Ra*128 + ((((kk<<2)+g) ^ (Ra&7)) << 4));
      }
      #pragma unroll
      for (int j=0;j<4;++j){
        int Rb = wc*64 + j*16 + r16;
        b[j] = *(const bf16x8*)((const char*)Bs + Rb*128 + ((((kk<<2)+g) ^ (Rb&7)) << 4));
      }
      #pragma unroll
      for (int i=0;i<4;++i)
        #pragma unroll
        for (int j=0;j<4;++j)
          acc[i][j] = __builtin_amdgcn_mfma_f32_16x16x32_bf16(a[i], b[j], acc[i][j], 0, 0, 0);
    }
    __syncthreads();
  }
  if (rope && n0 < 2560){
    float qsc = (n0 < 2048) ? 0.125f : 1.0f;   // fold 1/sqrt(HD) into q
    #pragma unroll
    for (int i=0;i<4;++i)
      #pragma unroll
      for (int r=0;r<4;++r){
        int row = m0 + wr*64 + i*16 + g*4 + r;
        int s = row & (SS-1);
        #pragma unroll
        for (int j=0;j<2;++j){
          int col = n0 + wc*64 + j*16 + r16;
          float c  = cosT[(s<<5) + (col&31)];
          float sn = sinT[(s<<5) + (col&31)];
          float x1 = acc[i][j][r], x2 = acc[i][j+2][r];
          C[(size_t)row*ldc + col]      = f2bf((x1*c - x2*sn)*qsc);
          C[(size_t)row*ldc + col + 32] = f2bf((x2*c + x1*sn)*qsc);
        }
      }
  } else {
    #pragma unroll
    for (int i=0;i<4;++i)
      #pragma unroll
      for (int j=0;j<4;++j)
        #pragma unroll
        for (int r=0;r<4;++r){
          int row = m0 + wr*64 + i*16 + g*4 + r;
          int col = n0 + wc*64 + j*16 + r16;
          C[(size_t)row*ldc + col] = f2bf(acc[i][j][r]);
        }
  }
}

// ---------------- Same GEMM, FP32 output (final O-projection): BK=64, XCD swizzle ----------------
__global__ __launch_bounds__(256) void gemm_btf_kernel(const short* __restrict__ A,
                                                       const short* __restrict__ Bm,
                                                       float* __restrict__ C,
                                                       int ldc, int K){
  __shared__ short As[128*64];
  __shared__ short Bs[128*64];
  const int tid = threadIdx.x;
  const int wave = tid >> 6, lane = tid & 63;
  const int g = lane >> 4, r16 = lane & 15;
  const int nx = gridDim.x, nwg = nx*gridDim.y;
  const int flat = blockIdx.y*nx + blockIdx.x;
  const int swz = (flat & 7)*(nwg >> 3) + (flat >> 3);
  const int m0 = (swz / nx) * 128, n0 = (swz % nx) * 128;
  const int wr = wave >> 1, wc = wave & 1;
  f32x4 acc[4][4] = {};
  for (int k0 = 0; k0 < K; k0 += 64){
    #pragma unroll
    for (int it = 0; it < 4; ++it){
      int ch = it*256 + wave*64 + lane;
      int row = ch >> 3, kc = ch & 7;
      int skc = kc ^ (row & 7);
      gload16(A  + (size_t)(m0+row)*K + k0 + skc*8, (char*)As + it*4096 + wave*1024);
      gload16(Bm + (size_t)(n0+row)*K + k0 + skc*8, (char*)Bs + it*4096 + wave*1024);
    }
    __syncthreads();
    #pragma unroll
    for (int kk=0; kk<2; ++kk){
      bf16x8 a[4], b[4];
      #pragma unroll
      for (int i=0;i<4;++i){
        int Ra = wr*64 + i*16 + r16;
        a[i] = *(const bf16x8*)((const char*)As + Ra*128 + ((((kk<<2)+g) ^ (Ra&7)) << 4));
      }
      #pragma unroll
      for (int j=0;j<4;++j){
        int Rb = wc*64 + j*16 + r16;
        b[j] = *(const bf16x8*)((const char*)Bs + Rb*128 + ((((kk<<2)+g) ^ (Rb&7)) << 4));
      }
      #pragma unroll
      for (int i=0;i<4;++i)
        #pragma unroll
        for (int j=0;j<4;++j)
          acc[i][j] = __builtin_amdgcn_mfma_f32_16x16x32_bf16(a[i], b[j], acc[i][j], 0, 0, 0);
    }
    __syncthreads();
  }
  #pragma unroll
  for (int i=0;i<4;++i)
    #pragma unroll
    for (int j=0;j<4;++j)
      #pragma unroll
      for (int r=0;r<4;++r){
        int row = m0 + wr*64 + i*16 + g*4 + r;
        int col = n0 + wc*64 + j*16 + r16;
        C[(size_t)row*ldc + col] = acc[i][j][r];
      }
}

// ---------------- Flash attention: QBLK=256 (8 waves x 32 q-rows), KVBLK=128 staged ----------------
// Staged tile = 128 keys (Ks[128][64] 8-chunk XOR rows; Vt[64][128] 16-chunk XOR rows, both
// r10-green layouts); computed as TWO 64-key halves, each verbatim r17's
// QK^T -> softmax(defer-max) -> PV for both q sub-blocks. 16 barrier pairs (was 32).
__global__ __launch_bounds__(512) void attn_kernel(const short* __restrict__ qkv,
                                                   const short* __restrict__ Vtg,
                                                   short* __restrict__ outb){
  __shared__ short Ks[128*64];      // [key][d], rows 128B
  __shared__ short Vt[64*128];      // V^T [d][key], rows 256B
  __shared__ short Ps[8*16*72];     // per-wave P^T [q=16][64 keys] pad->72 (reused)
  const int tid = threadIdx.x;
  const int wave = tid >> 6, lane = tid & 63;
  const int g = lane >> 4, r16 = lane & 15;
  const int qt = blockIdx.x, h = blockIdx.y, b = blockIdx.z;
  const int hkv = h >> 2;                       // GQA repeat_interleave: h//4
  const size_t row0 = (size_t)b * SS;
  const int qrow0 = qt*256 + wave*32;
  const short* qbase  = qkv + (row0 + qrow0)*NQKV + h*HD;
  const short* kbase  = qkv + row0*NQKV + DIM + hkv*HD;
  const short* vtbase = Vtg + ((size_t)(b*NKV + hkv)*64)*SS;

  // Q fragments (B-operand) for the two q sub-blocks: rows r16 (A) and 16+r16 (B)
  bf16x8 qfA[2], qfB[2];
  #pragma unroll
  for (int kk=0;kk<2;++kk){
    qfA[kk] = *(const bf16x8*)(qbase + (size_t)r16*NQKV      + kk*32 + g*8);
    qfB[kk] = *(const bf16x8*)(qbase + (size_t)(16+r16)*NQKV + kk*32 + g*8);
  }

  f32x4 oaccA[4] = {}, oaccB[4] = {};   // O^T[d=j*16+g*4+r][q=r16]
  float MA = -6.0e29f, MB = -6.0e29f;   // running max, log2 units
  float lA = 0.f, lB = 0.f;

  short* pwv = &Ps[wave*16*72];

  // staging: each thread 2 K chunks {tid, tid+512} + 2 V^T chunks {tid, tid+512}
  // K chunk ch: row=ch>>3 (128 rows), c3=ch&7, src swizzle c3^(row&7)   (r10 pattern)
  // V chunk ch: d=ch>>4 (64 rows),   c16=ch&15, src swizzle c16^(d&15)  (r10 pattern)
  const int kr0row = tid >> 3,        kr0c = tid & 7;
  const int kr1row = (tid+512) >> 3,  kr1c = (tid+512) & 7;
  const int vr0d   = tid >> 4,        vr0c = tid & 15;
  const int vr1d   = (tid+512) >> 4,  vr1c = (tid+512) & 15;
  const size_t koff0 = (size_t)kr0row*NQKV + ((kr0c ^ (kr0row&7)) << 3);
  const size_t koff1 = (size_t)kr1row*NQKV + ((kr1c ^ (kr1row&7)) << 3);
  const size_t voff0 = (size_t)vr0d*SS + ((vr0c ^ (vr0d&15)) << 3);
  const size_t voff1 = (size_t)vr1d*SS + ((vr1c ^ (vr1d&15)) << 3);

  auto LOADR = [&](int s0, bf16x8& k0r, bf16x8& k1r, bf16x8& v0r, bf16x8& v1r){
    k0r = *(const bf16x8*)(kbase + (size_t)s0*NQKV + koff0);
    k1r = *(const bf16x8*)(kbase + (size_t)s0*NQKV + koff1);
    v0r = *(const bf16x8*)(vtbase + voff0 + s0);
    v1r = *(const bf16x8*)(vtbase + voff1 + s0);
  };
  auto WRITE = [&](bf16x8 k0r, bf16x8 k1r, bf16x8 v0r, bf16x8 v1r){
    *(bf16x8*)((char*)Ks + tid*16)        = k0r;
    *(bf16x8*)((char*)Ks + (tid+512)*16)  = k1r;
    *(bf16x8*)((char*)Vt + tid*16)        = v0r;
    *(bf16x8*)((char*)Vt + (tid+512)*16)  = v1r;
  };

  { bf16x8 a,bb2,c,d; LOADR(0, a,bb2,c,d); WRITE(a,bb2,c,d); }
  __syncthreads();

  const int NT = SS/128;
  for (int t = 0; t < NT; ++t){
    bool more = (t+1 < NT);
    bf16x8 krn0, krn1, vrn0, vrn1;
    if (more) LOADR((t+1)*128, krn0, krn1, vrn0, vrn1);  // issue now; waits land at WRITE

    #pragma unroll
    for (int kh=0; kh<2; ++kh){          // two 64-key halves of the staged tile
      // ---- QK^T for both q sub-blocks ----
      f32x4 sA[4], sB[4];
      __builtin_amdgcn_s_setprio(1);
      #pragma unroll
      for (int t2=0;t2<4;++t2){
        f32x4 ca = {}, cb = {};
        #pragma unroll
        for (int kk=0;kk<2;++kk){
          int krow = kh*64 + t2*16 + r16;
          const bf16x8* kp = (const bf16x8*)((const char*)Ks + krow*128 +
                              ((((kk<<2)+g) ^ (krow&7)) << 4));
          ca = __builtin_amdgcn_mfma_f32_16x16x32_bf16(*kp, qfA[kk], ca, 0,0,0);
          cb = __builtin_amdgcn_mfma_f32_16x16x32_bf16(*kp, qfB[kk], cb, 0,0,0);
        }
        sA[t2] = ca; sB[t2] = cb;
      }
      __builtin_amdgcn_s_setprio(0);

      // ---- softmax + PV, q sub-block A then B (Ps reused; same-wave DS order) ----
      #pragma unroll
      for (int half=0; half<2; ++half){
        f32x4* sacc = half ? sB : sA;
        f32x4* oaccT = half ? oaccB : oaccA;
        float& M = half ? MB : MA;
        float& lrow = half ? lB : lA;

        float m01 = fmaxf(fmaxf(sacc[0][0], sacc[0][1]), fmaxf(sacc[0][2], sacc[0][3]));
        float m23 = fmaxf(fmaxf(sacc[1][0], sacc[1][1]), fmaxf(sacc[1][2], sacc[1][3]));
        float m45 = fmaxf(fmaxf(sacc[2][0], sacc[2][1]), fmaxf(sacc[2][2], sacc[2][3]));
        float m67 = fmaxf(fmaxf(sacc[3][0], sacc[3][1]), fmaxf(sacc[3][2], sacc[3][3]));
        float mx = fmaxf(fmaxf(m01, m23), fmaxf(m45, m67));
        mx = fmaxf(mx, __shfl_xor(mx, 16));
        mx = fmaxf(mx, __shfl_xor(mx, 32));
        float mxl = mx * L2E;
        if (__any(mxl > M + 11.5f)){      // wave-uniform rescale branch
          float Mnew = fmaxf(M, mxl);
          float al;
          { float a = M - Mnew; asm("v_exp_f32 %0, %1" : "=v"(al) : "v"(a)); }
          lrow *= al;
          #pragma unroll
          for (int j=0;j<4;++j)
            #pragma unroll
            for (int r=0;r<4;++r) oaccT[j][r] *= al;
          M = Mnew;
        }
        float s4[4] = {0.f,0.f,0.f,0.f};
        u32 pb[4][2];
        #pragma unroll
        for (int t2=0;t2<4;++t2){
          float p[4];
          #pragma unroll
          for (int r=0;r<4;++r){
            float a = fmaf(sacc[t2][r], L2E, -M);
            asm("v_exp_f32 %0, %1" : "=v"(p[r]) : "v"(a));
            s4[r] += p[r];
          }
          asm("v_cvt_pk_bf16_f32 %0, %1, %2" : "=v"(pb[t2][0]) : "v"(p[0]), "v"(p[1]));
          asm("v_cvt_pk_bf16_f32 %0, %1, %2" : "=v"(pb[t2][1]) : "v"(p[2]), "v"(p[3]));
        }
        float sum = (s4[0]+s4[1]) + (s4[2]+s4[3]);
        sum += __shfl_xor(sum, 16);
        sum += __shfl_xor(sum, 32);
        lrow += sum;

        #pragma unroll
        for (int t2=0;t2<4;++t2)
          *(u32x2*)&pwv[r16*72 + t2*16 + g*4] = (u32x2){pb[t2][0], pb[t2][1]};
        __builtin_amdgcn_s_setprio(1);
        #pragma unroll
        for (int kki=0;kki<2;++kki){
          bf16x8 pf = *(const bf16x8*)&pwv[r16*72 + 32*kki + g*8];
          int kkg = kh*2 + kki;          // key-chunk group within the 128-key tile
          #pragma unroll
          for (int j=0;j<4;++j){
            int d = j*16 + r16;
            const bf16x8* vp = (const bf16x8*)((const char*)Vt + d*256 +
                                ((((kkg<<2)+g) ^ (d&15)) << 4));
            oaccT[j] = __builtin_amdgcn_mfma_f32_16x16x32_bf16(*vp, pf, oaccT[j], 0,0,0);
          }
        }
        __builtin_amdgcn_s_setprio(0);
      }
    }

    if (more){
      __syncthreads();                  // all waves done READING Ks/Vt (full drain)
      WRITE(krn0, krn1, vrn0, vrn1);    // overwrite single buffer with tile t+1
      __syncthreads();                  // writes visible to all waves
    }
  }

  // epilogue: both q sub-blocks
  {
    float inv = 1.0f / lA;
    short* orow = outb + (row0 + qrow0 + r16)*(size_t)DIM + h*HD;
    #pragma unroll
    for (int j=0;j<4;++j){
      bf16x4s ov;
      #pragma unroll
      for (int r=0;r<4;++r) ov[r] = f2bf(oaccA[j][r]*inv);
      *(bf16x4s*)&orow[j*16 + g*4] = ov;
    }
  }
  {
    float inv = 1.0f / lB;
    short* orow = outb + (row0 + qrow0 + 16 + r16)*(size_t)DIM + h*HD;
    #pragma unroll
    for (int j=0;j<4;++j){
      bf16x4s ov;
      #pragma unroll
      for (int r=0;r<4;++r) ov[r] = f2bf(oaccB[j][r]*inv);
      *(bf16x4s*)&orow[j*16 + g*4] = ov;
    }
  }
}

extern "C" void kernel_launch(void* const* d_in, const int* in_sizes, int n_in,
                              void* d_out, int out_size, void* d_ws, size_t ws_size,
                              hipStream_t stream){
  const float* x  = (const float*)d_in[0];
  const float* wq = (const float*)d_in[1];
  const float* wk = (const float*)d_in[2];
  const float* wv = (const float*)d_in[3];
  const float* wo = (const float*)d_in[4];
  float* outf = (float*)d_out;   // FP32 output [4096, 2048]

  // Workspace (48.5 MB, time-shared):
  //   [0,16M):  wqkvb (12M, early) THEN attnb (16M, late)
  //   [16,24M): wob
  //   [24,48M): qkv
  //   [48,48.5M): cos/sin tables
  // d_out (32MB fp32) time-shared: [0,16M) xb bf16 (dead after QKV GEMM),
  //   [16,20M) Vtg bf16 V^T (dead before final GEMM writes d_out).
  char* ws = (char*)d_ws;
  short* wqkvb = (short*)(ws);
  short* attnb = (short*)(ws);
  short* wob   = (short*)(ws + 16777216);
  short* qkv   = (short*)(ws + 25165824);
  float* cosT  = (float*)(ws + 50331648);
  float* sinT  = (float*)(ws + 50593792);
  short* xb    = (short*)d_out;
  short* Vtg   = (short*)((char*)d_out + 16777216);

  cvt_all_kernel<<<18688, 256, 0, stream>>>(x, wq, wk, wv, wo, xb, wqkvb, wob, cosT, sinT);

  // QKV projection with fused RoPE epilogue: [4096,2048] x [3072,2048]^T -> qkv
  gemm_bt_kernel<<<dim3(NQKV/128, MROWS/128), 256, 0, stream>>>(xb, wqkvb, qkv, NQKV, KDIM,
                                                                cosT, sinT, 1);
  // materialize V^T once per (b,hkv)
  vT_kernel<<<dim3(SS/64, NKV, BB), 256, 0, stream>>>(qkv, Vtg);
  // attention (writes attnb, aliasing the now-dead wqkvb)
  attn_kernel<<<dim3(SS/256, NH, BB), 512, 0, stream>>>(qkv, Vtg, attnb);
  // O projection: [4096,2048] x [2048,2048]^T -> d_out as FP32
  gemm_btf_kernel<<<dim3(DIM/128, MROWS/128), 256, 0, stream>>>(attnb, wob, outf, DIM, KDIM);
}

// Round 21
// 239.761 us; speedup vs baseline: 1.1089x; 1.1089x over previous
//
#include <hip/hip_runtime.h>
#include <hip/hip_bf16.h>

typedef __attribute__((ext_vector_type(8))) short bf16x8;
typedef __attribute__((ext_vector_type(4))) short bf16x4s;
typedef __attribute__((ext_vector_type(4))) float f32x4;
typedef __attribute__((ext_vector_type(2))) unsigned int u32x2;
typedef unsigned int u32;

#define DIM 2048
#define NH 32
#define NKV 8
#define HD 64
#define BB 2
#define SS 2048
#define MROWS (BB*SS)     // 4096
#define NQKV 3072         // 2048 q + 512 k + 512 v columns
#define KDIM 2048
#define L2E 1.44269504f

__device__ __forceinline__ short f2bf(float f){
  u32 u = __float_as_uint(f);
  u32 r = u + 0x7fffu + ((u >> 16) & 1u);   // RNE
  return (short)(r >> 16);
}
__device__ __forceinline__ float bf2f(short s){
  return __uint_as_float(((u32)(unsigned short)s) << 16);
}

// async global->LDS, 16B per lane; dest must be wave-uniform base (+lane*16 implicit)
__device__ __forceinline__ void gload16(const void* g, void* l){
  __builtin_amdgcn_global_load_lds((const __attribute__((address_space(1))) u32*)g,
                                   (__attribute__((address_space(3))) u32*)l, 16, 0, 0);
}

// ---------------- fused fp32->bf16 convert of all 5 inputs + RoPE tables (1 launch) ----------------
__global__ __launch_bounds__(256) void cvt_all_kernel(const float* __restrict__ x,
                                                      const float* __restrict__ wq,
                                                      const float* __restrict__ wk,
                                                      const float* __restrict__ wv,
                                                      const float* __restrict__ wo,
                                                      short* __restrict__ xb,
                                                      short* __restrict__ wqkvb,
                                                      short* __restrict__ wob,
                                                      float* __restrict__ cosT,
                                                      float* __restrict__ sinT){
  int bid = blockIdx.x;
  if (bid >= 18432){   // RoPE tables: 256 blocks, idx over S*32
    int idx = (bid-18432)*256 + threadIdx.x;
    int s = idx >> 5, i = idx & 31;
    float inv = powf(10000.f, -(float)i * (1.f/32.f));
    float f = (float)s * inv;
    cosT[idx] = cosf(f);
    sinT[idx] = sinf(f);
    return;
  }
  int i = bid*256 + threadIdx.x;
  const float* src; short* dst; int off;
  if      (bid <  8192){ src = x;  dst = xb;              off = 0; }
  else if (bid < 12288){ src = wq; dst = wqkvb;           off = 2097152; }
  else if (bid < 13312){ src = wk; dst = wqkvb+2048*2048; off = 3145728; }
  else if (bid < 14336){ src = wv; dst = wqkvb+2560*2048; off = 3407872; }
  else                 { src = wo; dst = wob;             off = 3670016; }
  int j = i - off;
  f32x4 v = ((const f32x4*)src)[j];
  bf16x4s o;
  #pragma unroll
  for (int t=0;t<4;++t) o[t] = f2bf(v[t]);
  ((bf16x4s*)dst)[j] = o;
}

// ---------------- V^T materialization: Vtg[b][hkv][d=64][S] = V[b][s][hkv][d] ----------------
__global__ __launch_bounds__(256) void vT_kernel(const short* __restrict__ qkv,
                                                 short* __restrict__ Vtg){
  __shared__ short T[64*72];
  const int tid = threadIdx.x;
  const int s0 = blockIdx.x*64, hkv = blockIdx.y, b = blockIdx.z;
  const short* vbase = qkv + (size_t)b*SS*NQKV + DIM + NKV*HD + hkv*HD;
  #pragma unroll
  for (int cc=0; cc<2; ++cc){
    int c = tid + cc*256;
    int s = c >> 3, dc = c & 7;
    bf16x8 v = *(const bf16x8*)(vbase + (size_t)(s0+s)*NQKV + dc*8);
    #pragma unroll
    for (int i=0;i<8;++i) T[(dc*8+i)*72 + s] = v[i];
  }
  __syncthreads();
  short* obase = Vtg + ((size_t)(b*NKV + hkv)*64)*SS;
  #pragma unroll
  for (int cc=0; cc<2; ++cc){
    int c = tid + cc*256;
    int d = c >> 3, sc = c & 7;
    *(bf16x8*)(obase + (size_t)d*SS + s0 + sc*8) = *(const bf16x8*)&T[d*72 + sc*8];
  }
}

// ---------------- GEMM (bf16 out, optional fused RoPE): BK=64, both-sides XOR swizzle ----------------
__global__ __launch_bounds__(256) void gemm_bt_kernel(const short* __restrict__ A,
                                                      const short* __restrict__ Bm,
                                                      short* __restrict__ C,
                                                      int ldc, int K,
                                                      const float* __restrict__ cosT,
                                                      const float* __restrict__ sinT,
                                                      int rope){
  __shared__ short As[128*64];   // 16KB, rows 128B, chunk-swizzled
  __shared__ short Bs[128*64];
  const int tid = threadIdx.x;
  const int wave = tid >> 6, lane = tid & 63;
  const int g = lane >> 4, r16 = lane & 15;
  const int m0 = blockIdx.y * 128, n0 = blockIdx.x * 128;
  const int wr = wave >> 1, wc = wave & 1;
  f32x4 acc[4][4] = {};
  for (int k0 = 0; k0 < K; k0 += 64){
    #pragma unroll
    for (int it = 0; it < 4; ++it){
      int ch = it*256 + wave*64 + lane;       // chunk 0..1023
      int row = ch >> 3, kc = ch & 7;
      int skc = kc ^ (row & 7);               // pre-swizzle SOURCE (rule #21)
      gload16(A  + (size_t)(m0+row)*K + k0 + skc*8, (char*)As + it*4096 + wave*1024);
      gload16(Bm + (size_t)(n0+row)*K + k0 + skc*8, (char*)Bs + it*4096 + wave*1024);
    }
    __syncthreads();
    #pragma unroll
    for (int kk=0; kk<2; ++kk){
      bf16x8 a[4], b[4];
      #pragma unroll
      for (int i=0;i<4;++i){
        int Ra = wr*64 + i*16 + r16;
        a[i] = *(const bf16x8*)((const char*)As + Ra*128 + ((((kk<<2)+g) ^ (Ra&7)) << 4));
      }
      #pragma unroll
      for (int j=0;j<4;++j){
        int Rb = wc*64 + j*16 + r16;
        b[j] = *(const bf16x8*)((const char*)Bs + Rb*128 + ((((kk<<2)+g) ^ (Rb&7)) << 4));
      }
      #pragma unroll
      for (int i=0;i<4;++i)
        #pragma unroll
        for (int j=0;j<4;++j)
          acc[i][j] = __builtin_amdgcn_mfma_f32_16x16x32_bf16(a[i], b[j], acc[i][j], 0, 0, 0);
    }
    __syncthreads();
  }
  if (rope && n0 < 2560){
    // rotation pairs: (col, col+32) = (acc[i][j], acc[i][j+2]) for j in {0,1}
    float qsc = (n0 < 2048) ? 0.125f : 1.0f;   // fold 1/sqrt(HD) into q
    #pragma unroll
    for (int i=0;i<4;++i)
      #pragma unroll
      for (int r=0;r<4;++r){
        int row = m0 + wr*64 + i*16 + g*4 + r;
        int s = row & (SS-1);
        #pragma unroll
        for (int j=0;j<2;++j){
          int col = n0 + wc*64 + j*16 + r16;
          float c  = cosT[(s<<5) + (col&31)];
          float sn = sinT[(s<<5) + (col&31)];
          float x1 = acc[i][j][r], x2 = acc[i][j+2][r];
          C[(size_t)row*ldc + col]      = f2bf((x1*c - x2*sn)*qsc);
          C[(size_t)row*ldc + col + 32] = f2bf((x2*c + x1*sn)*qsc);
        }
      }
  } else {
    #pragma unroll
    for (int i=0;i<4;++i)
      #pragma unroll
      for (int j=0;j<4;++j)
        #pragma unroll
        for (int r=0;r<4;++r){
          int row = m0 + wr*64 + i*16 + g*4 + r;
          int col = n0 + wc*64 + j*16 + r16;
          C[(size_t)row*ldc + col] = f2bf(acc[i][j][r]);
        }
  }
}

// ---------------- Same GEMM, FP32 output (final O-projection): BK=64 ----------------
__global__ __launch_bounds__(256) void gemm_btf_kernel(const short* __restrict__ A,
                                                       const short* __restrict__ Bm,
                                                       float* __restrict__ C,
                                                       int ldc, int K){
  __shared__ short As[128*64];
  __shared__ short Bs[128*64];
  const int tid = threadIdx.x;
  const int wave = tid >> 6, lane = tid & 63;
  const int g = lane >> 4, r16 = lane & 15;
  const int m0 = blockIdx.y * 128, n0 = blockIdx.x * 128;
  const int wr = wave >> 1, wc = wave & 1;
  f32x4 acc[4][4] = {};
  for (int k0 = 0; k0 < K; k0 += 64){
    #pragma unroll
    for (int it = 0; it < 4; ++it){
      int ch = it*256 + wave*64 + lane;
      int row = ch >> 3, kc = ch & 7;
      int skc = kc ^ (row & 7);
      gload16(A  + (size_t)(m0+row)*K + k0 + skc*8, (char*)As + it*4096 + wave*1024);
      gload16(Bm + (size_t)(n0+row)*K + k0 + skc*8, (char*)Bs + it*4096 + wave*1024);
    }
    __syncthreads();
    #pragma unroll
    for (int kk=0; kk<2; ++kk){
      bf16x8 a[4], b[4];
      #pragma unroll
      for (int i=0;i<4;++i){
        int Ra = wr*64 + i*16 + r16;
        a[i] = *(const bf16x8*)((const char*)As + Ra*128 + ((((kk<<2)+g) ^ (Ra&7)) << 4));
      }
      #pragma unroll
      for (int j=0;j<4;++j){
        int Rb = wc*64 + j*16 + r16;
        b[j] = *(const bf16x8*)((const char*)Bs + Rb*128 + ((((kk<<2)+g) ^ (Rb&7)) << 4));
      }
      #pragma unroll
      for (int i=0;i<4;++i)
        #pragma unroll
        for (int j=0;j<4;++j)
          acc[i][j] = __builtin_amdgcn_mfma_f32_16x16x32_bf16(a[i], b[j], acc[i][j], 0, 0, 0);
    }
    __syncthreads();
  }
  #pragma unroll
  for (int i=0;i<4;++i)
    #pragma unroll
    for (int j=0;j<4;++j)
      #pragma unroll
      for (int r=0;r<4;++r){
        int row = m0 + wr*64 + i*16 + g*4 + r;
        int col = n0 + wc*64 + j*16 + r16;
        C[(size_t)row*ldc + col] = acc[i][j][r];
      }
}

// ---------------- Flash attention: QBLK=256 (8 waves x 32 q-rows), KVBLK=64 ----------------
// r17 optimum: single-buffer LDS (34.4KB), reg-staged prefetch, 2-chain ILP per wave,
// max-tracked defer-max softmax, per-wave Ps time-shared between sub-blocks. VGPR 60.
__global__ __launch_bounds__(512) void attn_kernel(const short* __restrict__ qkv,
                                                   const short* __restrict__ Vtg,
                                                   short* __restrict__ outb){
  __shared__ short Ks[64*64];       // [key][d], 8-chunk XOR-swizzled rows (128B)
  __shared__ short Vt[64*64];       // V^T [d][key], 8-chunk XOR-swizzled rows (128B)
  __shared__ short Ps[8*16*72];     // per-wave P^T [q=16][64 keys] pad->72 (reused A/B)
  const int tid = threadIdx.x;
  const int wave = tid >> 6, lane = tid & 63;
  const int g = lane >> 4, r16 = lane & 15;
  const int qt = blockIdx.x, h = blockIdx.y, b = blockIdx.z;
  const int hkv = h >> 2;                       // GQA repeat_interleave: h//4
  const size_t row0 = (size_t)b * SS;
  const int qrow0 = qt*256 + wave*32;
  const short* qbase  = qkv + (row0 + qrow0)*NQKV + h*HD;
  const short* kbase  = qkv + row0*NQKV + DIM + hkv*HD;
  const short* vtbase = Vtg + ((size_t)(b*NKV + hkv)*64)*SS;

  // Q fragments (B-operand) for the two sub-blocks: rows r16 (A) and 16+r16 (B)
  bf16x8 qfA[2], qfB[2];
  #pragma unroll
  for (int kk=0;kk<2;++kk){
    qfA[kk] = *(const bf16x8*)(qbase + (size_t)r16*NQKV      + kk*32 + g*8);
    qfB[kk] = *(const bf16x8*)(qbase + (size_t)(16+r16)*NQKV + kk*32 + g*8);
  }

  f32x4 oaccA[4] = {}, oaccB[4] = {};   // O^T[d=j*16+g*4+r][q=r16]
  float MA = -6.0e29f, MB = -6.0e29f;   // running max, log2 units
  float lA = 0.f, lB = 0.f;

  short* pwv = &Ps[wave*16*72];

  // staging: each thread 1 K chunk + 1 V^T chunk; sources pre-swizzled (rule #21)
  const int trow = tid >> 3, tc3 = tid & 7;
  const size_t koff = (size_t)trow*NQKV + ((tc3 ^ (trow&7)) << 3);
  const size_t voff = (size_t)trow*SS   + ((tc3 ^ (trow&7)) << 3);

  auto LOADR = [&](int s0, bf16x8& kr, bf16x8& vr){
    kr = *(const bf16x8*)(kbase + (size_t)s0*NQKV + koff);
    vr = *(const bf16x8*)(vtbase + voff + s0);
  };
  auto WRITE = [&](bf16x8 kr, bf16x8 vr){
    *(bf16x8*)((char*)Ks + tid*16) = kr;
    *(bf16x8*)((char*)Vt + tid*16) = vr;
  };

  { bf16x8 k0r, v0r; LOADR(0, k0r, v0r); WRITE(k0r, v0r); }
  __syncthreads();

  const int NT = SS/64;
  for (int t = 0; t < NT; ++t){
    bool more = (t+1 < NT);
    bf16x8 krn, vrn;
    if (more) LOADR((t+1)*64, krn, vrn);   // reg loads issue now; waitcnt lands at WRITE

    // ---- QK^T for both sub-blocks (two independent MFMA chains) ----
    f32x4 sA[4], sB[4];
    __builtin_amdgcn_s_setprio(1);
    #pragma unroll
    for (int t2=0;t2<4;++t2){
      f32x4 ca = {}, cb = {};
      #pragma unroll
      for (int kk=0;kk<2;++kk){
        int krow = t2*16 + r16;
        const bf16x8* kp = (const bf16x8*)((const char*)Ks + krow*128 +
                            ((((kk<<2)+g) ^ (krow&7)) << 4));
        ca = __builtin_amdgcn_mfma_f32_16x16x32_bf16(*kp, qfA[kk], ca, 0,0,0);
        cb = __builtin_amdgcn_mfma_f32_16x16x32_bf16(*kp, qfB[kk], cb, 0,0,0);
      }
      sA[t2] = ca; sB[t2] = cb;
    }
    __builtin_amdgcn_s_setprio(0);

    // ---- softmax + PV, sub-block A then B (Ps buffer reused; same-wave DS order) ----
    #pragma unroll
    for (int half=0; half<2; ++half){
      f32x4* sacc = half ? sB : sA;
      f32x4* oaccT = half ? oaccB : oaccA;
      float& M = half ? MB : MA;
      float& lrow = half ? lB : lA;

      float m01 = fmaxf(fmaxf(sacc[0][0], sacc[0][1]), fmaxf(sacc[0][2], sacc[0][3]));
      float m23 = fmaxf(fmaxf(sacc[1][0], sacc[1][1]), fmaxf(sacc[1][2], sacc[1][3]));
      float m45 = fmaxf(fmaxf(sacc[2][0], sacc[2][1]), fmaxf(sacc[2][2], sacc[2][3]));
      float m67 = fmaxf(fmaxf(sacc[3][0], sacc[3][1]), fmaxf(sacc[3][2], sacc[3][3]));
      float mx = fmaxf(fmaxf(m01, m23), fmaxf(m45, m67));
      mx = fmaxf(mx, __shfl_xor(mx, 16));
      mx = fmaxf(mx, __shfl_xor(mx, 32));
      float mxl = mx * L2E;
      if (__any(mxl > M + 11.5f)){      // wave-uniform rescale branch
        float Mnew = fmaxf(M, mxl);
        float al;
        { float a = M - Mnew; asm("v_exp_f32 %0, %1" : "=v"(al) : "v"(a)); }
        lrow *= al;
        #pragma unroll
        for (int j=0;j<4;++j)
          #pragma unroll
          for (int r=0;r<4;++r) oaccT[j][r] *= al;
        M = Mnew;
      }
      float s4[4] = {0.f,0.f,0.f,0.f};
      u32 pb[4][2];
      #pragma unroll
      for (int t2=0;t2<4;++t2){
        float p[4];
        #pragma unroll
        for (int r=0;r<4;++r){
          float a = fmaf(sacc[t2][r], L2E, -M);
          asm("v_exp_f32 %0, %1" : "=v"(p[r]) : "v"(a));
          s4[r] += p[r];
        }
        asm("v_cvt_pk_bf16_f32 %0, %1, %2" : "=v"(pb[t2][0]) : "v"(p[0]), "v"(p[1]));
        asm("v_cvt_pk_bf16_f32 %0, %1, %2" : "=v"(pb[t2][1]) : "v"(p[2]), "v"(p[3]));
      }
      float sum = (s4[0]+s4[1]) + (s4[2]+s4[3]);
      sum += __shfl_xor(sum, 16);
      sum += __shfl_xor(sum, 32);
      lrow += sum;

      #pragma unroll
      for (int t2=0;t2<4;++t2)
        *(u32x2*)&pwv[r16*72 + t2*16 + g*4] = (u32x2){pb[t2][0], pb[t2][1]};
      __builtin_amdgcn_s_setprio(1);
      #pragma unroll
      for (int kki=0;kki<2;++kki){
        bf16x8 pf = *(const bf16x8*)&pwv[r16*72 + 32*kki + g*8];
        #pragma unroll
        for (int j=0;j<4;++j){
          int d = j*16 + r16;
          const bf16x8* vp = (const bf16x8*)((const char*)Vt + d*128 +
                              ((((kki<<2)+g) ^ (d&7)) << 4));
          oaccT[j] = __builtin_amdgcn_mfma_f32_16x16x32_bf16(*vp, pf, oaccT[j], 0,0,0);
        }
      }
      __builtin_amdgcn_s_setprio(0);
    }

    if (more){
      __syncthreads();                // all waves done READING Ks/Vt (full lgkm drain)
      WRITE(krn, vrn);                // overwrite single buffer with tile t+1
      __syncthreads();                // writes visible to all waves
    }
  }

  // epilogue: both sub-blocks
  {
    float inv = 1.0f / lA;
    short* orow = outb + (row0 + qrow0 + r16)*(size_t)DIM + h*HD;
    #pragma unroll
    for (int j=0;j<4;++j){
      bf16x4s ov;
      #pragma unroll
      for (int r=0;r<4;++r) ov[r] = f2bf(oaccA[j][r]*inv);
      *(bf16x4s*)&orow[j*16 + g*4] = ov;
    }
  }
  {
    float inv = 1.0f / lB;
    short* orow = outb + (row0 + qrow0 + 16 + r16)*(size_t)DIM + h*HD;
    #pragma unroll
    for (int j=0;j<4;++j){
      bf16x4s ov;
      #pragma unroll
      for (int r=0;r<4;++r) ov[r] = f2bf(oaccB[j][r]*inv);
      *(bf16x4s*)&orow[j*16 + g*4] = ov;
    }
  }
}

extern "C" void kernel_launch(void* const* d_in, const int* in_sizes, int n_in,
                              void* d_out, int out_size, void* d_ws, size_t ws_size,
                              hipStream_t stream){
  const float* x  = (const float*)d_in[0];
  const float* wq = (const float*)d_in[1];
  const float* wk = (const float*)d_in[2];
  const float* wv = (const float*)d_in[3];
  const float* wo = (const float*)d_in[4];
  float* outf = (float*)d_out;   // FP32 output [4096, 2048]

  // Workspace (48.5 MB, time-shared):
  //   [0,16M):  wqkvb (12M, early) THEN attnb (16M, late)
  //   [16,24M): wob
  //   [24,48M): qkv
  //   [48,48.5M): cos/sin tables
  // d_out (32MB fp32) time-shared: [0,16M) xb bf16 (dead after QKV GEMM),
  //   [16,20M) Vtg bf16 V^T (dead before final GEMM writes d_out).
  char* ws = (char*)d_ws;
  short* wqkvb = (short*)(ws);
  short* attnb = (short*)(ws);
  short* wob   = (short*)(ws + 16777216);
  short* qkv   = (short*)(ws + 25165824);
  float* cosT  = (float*)(ws + 50331648);
  float* sinT  = (float*)(ws + 50593792);
  short* xb    = (short*)d_out;
  short* Vtg   = (short*)((char*)d_out + 16777216);

  cvt_all_kernel<<<18688, 256, 0, stream>>>(x, wq, wk, wv, wo, xb, wqkvb, wob, cosT, sinT);

  // QKV projection with fused RoPE epilogue: [4096,2048] x [3072,2048]^T -> qkv
  gemm_bt_kernel<<<dim3(NQKV/128, MROWS/128), 256, 0, stream>>>(xb, wqkvb, qkv, NQKV, KDIM,
                                                                cosT, sinT, 1);
  // materialize V^T once per (b,hkv)
  vT_kernel<<<dim3(SS/64, NKV, BB), 256, 0, stream>>>(qkv, Vtg);
  // attention (writes attnb, aliasing the now-dead wqkvb)
  attn_kernel<<<dim3(SS/256, NH, BB), 512, 0, stream>>>(qkv, Vtg, attnb);
  // O projection: [4096,2048] x [2048,2048]^T -> d_out as FP32
  gemm_btf_kernel<<<dim3(DIM/128, MROWS/128), 256, 0, stream>>>(attnb, wob, outf, DIM, KDIM);
}

// Round 22
// 239.008 us; speedup vs baseline: 1.1124x; 1.0032x over previous
//
#include <hip/hip_runtime.h>
#include <hip/hip_bf16.h>

typedef __attribute__((ext_vector_type(8))) short bf16x8;
typedef __attribute__((ext_vector_type(4))) short bf16x4s;
typedef __attribute__((ext_vector_type(4))) float f32x4;
typedef __attribute__((ext_vector_type(2))) unsigned int u32x2;
typedef unsigned int u32;

#define DIM 2048
#define NH 32
#define NKV 8
#define HD 64
#define BB 2
#define SS 2048
#define MROWS (BB*SS)     // 4096
#define NQKV 3072         // 2048 q + 512 k + 512 v columns
#define KDIM 2048
#define L2E 1.44269504f

__device__ __forceinline__ short f2bf(float f){
  u32 u = __float_as_uint(f);
  u32 r = u + 0x7fffu + ((u >> 16) & 1u);   // RNE
  return (short)(r >> 16);
}
__device__ __forceinline__ float bf2f(short s){
  return __uint_as_float(((u32)(unsigned short)s) << 16);
}

// async global->LDS, 16B per lane; dest must be wave-uniform base (+lane*16 implicit)
__device__ __forceinline__ void gload16(const void* g, void* l){
  __builtin_amdgcn_global_load_lds((const __attribute__((address_space(1))) u32*)g,
                                   (__attribute__((address_space(3))) u32*)l, 16, 0, 0);
}

// ---------------- fused fp32->bf16 convert of all 5 inputs + RoPE tables (1 launch) ----------------
__global__ __launch_bounds__(256) void cvt_all_kernel(const float* __restrict__ x,
                                                      const float* __restrict__ wq,
                                                      const float* __restrict__ wk,
                                                      const float* __restrict__ wv,
                                                      const float* __restrict__ wo,
                                                      short* __restrict__ xb,
                                                      short* __restrict__ wqkvb,
                                                      short* __restrict__ wob,
                                                      float* __restrict__ cosT,
                                                      float* __restrict__ sinT){
  int bid = blockIdx.x;
  if (bid >= 18432){   // RoPE tables: 256 blocks, idx over S*32
    int idx = (bid-18432)*256 + threadIdx.x;
    int s = idx >> 5, i = idx & 31;
    float inv = powf(10000.f, -(float)i * (1.f/32.f));
    float f = (float)s * inv;
    cosT[idx] = cosf(f);
    sinT[idx] = sinf(f);
    return;
  }
  int i = bid*256 + threadIdx.x;
  const float* src; short* dst; int off;
  if      (bid <  8192){ src = x;  dst = xb;              off = 0; }
  else if (bid < 12288){ src = wq; dst = wqkvb;           off = 2097152; }
  else if (bid < 13312){ src = wk; dst = wqkvb+2048*2048; off = 3145728; }
  else if (bid < 14336){ src = wv; dst = wqkvb+2560*2048; off = 3407872; }
  else                 { src = wo; dst = wob;             off = 3670016; }
  int j = i - off;
  f32x4 v = ((const f32x4*)src)[j];
  bf16x4s o;
  #pragma unroll
  for (int t=0;t<4;++t) o[t] = f2bf(v[t]);
  ((bf16x4s*)dst)[j] = o;
}

// ---------------- GEMM (bf16 out) with fused RoPE (q/k cols) + V^T scatter (v cols) ----------------
// BK=64, both-sides XOR swizzle, r10-green 2-barrier structure.
// rope!=0: n0<2048 q (RoPE + 0.125), n0 in [2048,2560) k (RoPE), n0>=2560 v -> Vtg transposed.
__global__ __launch_bounds__(256) void gemm_bt_kernel(const short* __restrict__ A,
                                                      const short* __restrict__ Bm,
                                                      short* __restrict__ C,
                                                      short* __restrict__ Vtg,
                                                      int ldc, int K,
                                                      const float* __restrict__ cosT,
                                                      const float* __restrict__ sinT,
                                                      int rope){
  __shared__ short As[128*64];   // 16KB, rows 128B, chunk-swizzled
  __shared__ short Bs[128*64];
  const int tid = threadIdx.x;
  const int wave = tid >> 6, lane = tid & 63;
  const int g = lane >> 4, r16 = lane & 15;
  const int m0 = blockIdx.y * 128, n0 = blockIdx.x * 128;
  const int wr = wave >> 1, wc = wave & 1;
  f32x4 acc[4][4] = {};
  for (int k0 = 0; k0 < K; k0 += 64){
    #pragma unroll
    for (int it = 0; it < 4; ++it){
      int ch = it*256 + wave*64 + lane;       // chunk 0..1023
      int row = ch >> 3, kc = ch & 7;
      int skc = kc ^ (row & 7);               // pre-swizzle SOURCE (rule #21)
      gload16(A  + (size_t)(m0+row)*K + k0 + skc*8, (char*)As + it*4096 + wave*1024);
      gload16(Bm + (size_t)(n0+row)*K + k0 + skc*8, (char*)Bs + it*4096 + wave*1024);
    }
    __syncthreads();
    #pragma unroll
    for (int kk=0; kk<2; ++kk){
      bf16x8 a[4], b[4];
      #pragma unroll
      for (int i=0;i<4;++i){
        int Ra = wr*64 + i*16 + r16;
        a[i] = *(const bf16x8*)((const char*)As + Ra*128 + ((((kk<<2)+g) ^ (Ra&7)) << 4));
      }
      #pragma unroll
      for (int j=0;j<4;++j){
        int Rb = wc*64 + j*16 + r16;
        b[j] = *(const bf16x8*)((const char*)Bs + Rb*128 + ((((kk<<2)+g) ^ (Rb&7)) << 4));
      }
      #pragma unroll
      for (int i=0;i<4;++i)
        #pragma unroll
        for (int j=0;j<4;++j)
          acc[i][j] = __builtin_amdgcn_mfma_f32_16x16x32_bf16(a[i], b[j], acc[i][j], 0, 0, 0);
    }
    __syncthreads();
  }
  if (rope && n0 < 2560){
    // rotation pairs: (col, col+32) = (acc[i][j], acc[i][j+2]) for j in {0,1}
    float qsc = (n0 < 2048) ? 0.125f : 1.0f;   // fold 1/sqrt(HD) into q
    #pragma unroll
    for (int i=0;i<4;++i)
      #pragma unroll
      for (int r=0;r<4;++r){
        int row = m0 + wr*64 + i*16 + g*4 + r;
        int s = row & (SS-1);
        #pragma unroll
        for (int j=0;j<2;++j){
          int col = n0 + wc*64 + j*16 + r16;
          float c  = cosT[(s<<5) + (col&31)];
          float sn = sinT[(s<<5) + (col&31)];
          float x1 = acc[i][j][r], x2 = acc[i][j+2][r];
          C[(size_t)row*ldc + col]      = f2bf((x1*c - x2*sn)*qsc);
          C[(size_t)row*ldc + col + 32] = f2bf((x2*c + x1*sn)*qsc);
        }
      }
  } else if (rope){
    // v columns: write V^T directly to Vtg[b][hkv][d][s] (bit-identical to the old vT copy)
    #pragma unroll
    for (int i=0;i<4;++i){
      int row = m0 + wr*64 + i*16 + g*4;        // rows row..row+3 share b and s-run
      int bb2 = row >> 11;
      int s = row & (SS-1);
      #pragma unroll
      for (int j=0;j<4;++j){
        int vcol = n0 + wc*64 + j*16 + r16 - 2560;
        int hkv = vcol >> 6, d = vcol & 63;
        short* dst = Vtg + ((size_t)(bb2*NKV + hkv)*64 + d)*SS + s;
        bf16x4s ov;
        #pragma unroll
        for (int r=0;r<4;++r) ov[r] = f2bf(acc[i][j][r]);
        *(bf16x4s*)dst = ov;
      }
    }
  } else {
    #pragma unroll
    for (int i=0;i<4;++i)
      #pragma unroll
      for (int j=0;j<4;++j)
        #pragma unroll
        for (int r=0;r<4;++r){
          int row = m0 + wr*64 + i*16 + g*4 + r;
          int col = n0 + wc*64 + j*16 + r16;
          C[(size_t)row*ldc + col] = f2bf(acc[i][j][r]);
        }
  }
}

// ---------------- Same GEMM, FP32 output (final O-projection): BK=64 ----------------
__global__ __launch_bounds__(256) void gemm_btf_kernel(const short* __restrict__ A,
                                                       const short* __restrict__ Bm,
                                                       float* __restrict__ C,
                                                       int ldc, int K){
  __shared__ short As[128*64];
  __shared__ short Bs[128*64];
  const int tid = threadIdx.x;
  const int wave = tid >> 6, lane = tid & 63;
  const int g = lane >> 4, r16 = lane & 15;
  const int m0 = blockIdx.y * 128, n0 = blockIdx.x * 128;
  const int wr = wave >> 1, wc = wave & 1;
  f32x4 acc[4][4] = {};
  for (int k0 = 0; k0 < K; k0 += 64){
    #pragma unroll
    for (int it = 0; it < 4; ++it){
      int ch = it*256 + wave*64 + lane;
      int row = ch >> 3, kc = ch & 7;
      int skc = kc ^ (row & 7);
      gload16(A  + (size_t)(m0+row)*K + k0 + skc*8, (char*)As + it*4096 + wave*1024);
      gload16(Bm + (size_t)(n0+row)*K + k0 + skc*8, (char*)Bs + it*4096 + wave*1024);
    }
    __syncthreads();
    #pragma unroll
    for (int kk=0; kk<2; ++kk){
      bf16x8 a[4], b[4];
      #pragma unroll
      for (int i=0;i<4;++i){
        int Ra = wr*64 + i*16 + r16;
        a[i] = *(const bf16x8*)((const char*)As + Ra*128 + ((((kk<<2)+g) ^ (Ra&7)) << 4));
      }
      #pragma unroll
      for (int j=0;j<4;++j){
        int Rb = wc*64 + j*16 + r16;
        b[j] = *(const bf16x8*)((const char*)Bs + Rb*128 + ((((kk<<2)+g) ^ (Rb&7)) << 4));
      }
      #pragma unroll
      for (int i=0;i<4;++i)
        #pragma unroll
        for (int j=0;j<4;++j)
          acc[i][j] = __builtin_amdgcn_mfma_f32_16x16x32_bf16(a[i], b[j], acc[i][j], 0, 0, 0);
    }
    __syncthreads();
  }
  #pragma unroll
  for (int i=0;i<4;++i)
    #pragma unroll
    for (int j=0;j<4;++j)
      #pragma unroll
      for (int r=0;r<4;++r){
        int row = m0 + wr*64 + i*16 + g*4 + r;
        int col = n0 + wc*64 + j*16 + r16;
        C[(size_t)row*ldc + col] = acc[i][j][r];
      }
}

// ---------------- Flash attention: QBLK=256 (8 waves x 32 q-rows), KVBLK=64 ----------------
// r17 optimum: single-buffer LDS (34.4KB), reg-staged prefetch, 2-chain ILP per wave,
// max-tracked defer-max softmax, per-wave Ps time-shared between sub-blocks. VGPR 60.
__global__ __launch_bounds__(512) void attn_kernel(const short* __restrict__ qkv,
                                                   const short* __restrict__ Vtg,
                                                   short* __restrict__ outb){
  __shared__ short Ks[64*64];       // [key][d], 8-chunk XOR-swizzled rows (128B)
  __shared__ short Vt[64*64];       // V^T [d][key], 8-chunk XOR-swizzled rows (128B)
  __shared__ short Ps[8*16*72];     // per-wave P^T [q=16][64 keys] pad->72 (reused A/B)
  const int tid = threadIdx.x;
  const int wave = tid >> 6, lane = tid & 63;
  const int g = lane >> 4, r16 = lane & 15;
  const int qt = blockIdx.x, h = blockIdx.y, b = blockIdx.z;
  const int hkv = h >> 2;                       // GQA repeat_interleave: h//4
  const size_t row0 = (size_t)b * SS;
  const int qrow0 = qt*256 + wave*32;
  const short* qbase  = qkv + (row0 + qrow0)*NQKV + h*HD;
  const short* kbase  = qkv + row0*NQKV + DIM + hkv*HD;
  const short* vtbase = Vtg + ((size_t)(b*NKV + hkv)*64)*SS;

  // Q fragments (B-operand) for the two sub-blocks: rows r16 (A) and 16+r16 (B)
  bf16x8 qfA[2], qfB[2];
  #pragma unroll
  for (int kk=0;kk<2;++kk){
    qfA[kk] = *(const bf16x8*)(qbase + (size_t)r16*NQKV      + kk*32 + g*8);
    qfB[kk] = *(const bf16x8*)(qbase + (size_t)(16+r16)*NQKV + kk*32 + g*8);
  }

  f32x4 oaccA[4] = {}, oaccB[4] = {};   // O^T[d=j*16+g*4+r][q=r16]
  float MA = -6.0e29f, MB = -6.0e29f;   // running max, log2 units
  float lA = 0.f, lB = 0.f;

  short* pwv = &Ps[wave*16*72];

  // staging: each thread 1 K chunk + 1 V^T chunk; sources pre-swizzled (rule #21)
  const int trow = tid >> 3, tc3 = tid & 7;
  const size_t koff = (size_t)trow*NQKV + ((tc3 ^ (trow&7)) << 3);
  const size_t voff = (size_t)trow*SS   + ((tc3 ^ (trow&7)) << 3);

  auto LOADR = [&](int s0, bf16x8& kr, bf16x8& vr){
    kr = *(const bf16x8*)(kbase + (size_t)s0*NQKV + koff);
    vr = *(const bf16x8*)(vtbase + voff + s0);
  };
  auto WRITE = [&](bf16x8 kr, bf16x8 vr){
    *(bf16x8*)((char*)Ks + tid*16) = kr;
    *(bf16x8*)((char*)Vt + tid*16) = vr;
  };

  { bf16x8 k0r, v0r; LOADR(0, k0r, v0r); WRITE(k0r, v0r); }
  __syncthreads();

  const int NT = SS/64;
  for (int t = 0; t < NT; ++t){
    bool more = (t+1 < NT);
    bf16x8 krn, vrn;
    if (more) LOADR((t+1)*64, krn, vrn);   // reg loads issue now; waitcnt lands at WRITE

    // ---- QK^T for both sub-blocks (two independent MFMA chains) ----
    f32x4 sA[4], sB[4];
    __builtin_amdgcn_s_setprio(1);
    #pragma unroll
    for (int t2=0;t2<4;++t2){
      f32x4 ca = {}, cb = {};
      #pragma unroll
      for (int kk=0;kk<2;++kk){
        int krow = t2*16 + r16;
        const bf16x8* kp = (const bf16x8*)((const char*)Ks + krow*128 +
                            ((((kk<<2)+g) ^ (krow&7)) << 4));
        ca = __builtin_amdgcn_mfma_f32_16x16x32_bf16(*kp, qfA[kk], ca, 0,0,0);
        cb = __builtin_amdgcn_mfma_f32_16x16x32_bf16(*kp, qfB[kk], cb, 0,0,0);
      }
      sA[t2] = ca; sB[t2] = cb;
    }
    __builtin_amdgcn_s_setprio(0);

    // ---- softmax + PV, sub-block A then B (Ps buffer reused; same-wave DS order) ----
    #pragma unroll
    for (int half=0; half<2; ++half){
      f32x4* sacc = half ? sB : sA;
      f32x4* oaccT = half ? oaccB : oaccA;
      float& M = half ? MB : MA;
      float& lrow = half ? lB : lA;

      float m01 = fmaxf(fmaxf(sacc[0][0], sacc[0][1]), fmaxf(sacc[0][2], sacc[0][3]));
      float m23 = fmaxf(fmaxf(sacc[1][0], sacc[1][1]), fmaxf(sacc[1][2], sacc[1][3]));
      float m45 = fmaxf(fmaxf(sacc[2][0], sacc[2][1]), fmaxf(sacc[2][2], sacc[2][3]));
      float m67 = fmaxf(fmaxf(sacc[3][0], sacc[3][1]), fmaxf(sacc[3][2], sacc[3][3]));
      float mx = fmaxf(fmaxf(m01, m23), fmaxf(m45, m67));
      mx = fmaxf(mx, __shfl_xor(mx, 16));
      mx = fmaxf(mx, __shfl_xor(mx, 32));
      float mxl = mx * L2E;
      if (__any(mxl > M + 11.5f)){      // wave-uniform rescale branch
        float Mnew = fmaxf(M, mxl);
        float al;
        { float a = M - Mnew; asm("v_exp_f32 %0, %1" : "=v"(al) : "v"(a)); }
        lrow *= al;
        #pragma unroll
        for (int j=0;j<4;++j)
          #pragma unroll
          for (int r=0;r<4;++r) oaccT[j][r] *= al;
        M = Mnew;
      }
      float s4[4] = {0.f,0.f,0.f,0.f};
      u32 pb[4][2];
      #pragma unroll
      for (int t2=0;t2<4;++t2){
        float p[4];
        #pragma unroll
        for (int r=0;r<4;++r){
          float a = fmaf(sacc[t2][r], L2E, -M);
          asm("v_exp_f32 %0, %1" : "=v"(p[r]) : "v"(a));
          s4[r] += p[r];
        }
        asm("v_cvt_pk_bf16_f32 %0, %1, %2" : "=v"(pb[t2][0]) : "v"(p[0]), "v"(p[1]));
        asm("v_cvt_pk_bf16_f32 %0, %1, %2" : "=v"(pb[t2][1]) : "v"(p[2]), "v"(p[3]));
      }
      float sum = (s4[0]+s4[1]) + (s4[2]+s4[3]);
      sum += __shfl_xor(sum, 16);
      sum += __shfl_xor(sum, 32);
      lrow += sum;

      #pragma unroll
      for (int t2=0;t2<4;++t2)
        *(u32x2*)&pwv[r16*72 + t2*16 + g*4] = (u32x2){pb[t2][0], pb[t2][1]};
      __builtin_amdgcn_s_setprio(1);
      #pragma unroll
      for (int kki=0;kki<2;++kki){
        bf16x8 pf = *(const bf16x8*)&pwv[r16*72 + 32*kki + g*8];
        #pragma unroll
        for (int j=0;j<4;++j){
          int d = j*16 + r16;
          const bf16x8* vp = (const bf16x8*)((const char*)Vt + d*128 +
                              ((((kki<<2)+g) ^ (d&7)) << 4));
          oaccT[j] = __builtin_amdgcn_mfma_f32_16x16x32_bf16(*vp, pf, oaccT[j], 0,0,0);
        }
      }
      __builtin_amdgcn_s_setprio(0);
    }

    if (more){
      __syncthreads();                // all waves done READING Ks/Vt (full lgkm drain)
      WRITE(krn, vrn);                // overwrite single buffer with tile t+1
      __syncthreads();                // writes visible to all waves
    }
  }

  // epilogue: both sub-blocks
  {
    float inv = 1.0f / lA;
    short* orow = outb + (row0 + qrow0 + r16)*(size_t)DIM + h*HD;
    #pragma unroll
    for (int j=0;j<4;++j){
      bf16x4s ov;
      #pragma unroll
      for (int r=0;r<4;++r) ov[r] = f2bf(oaccA[j][r]*inv);
      *(bf16x4s*)&orow[j*16 + g*4] = ov;
    }
  }
  {
    float inv = 1.0f / lB;
    short* orow = outb + (row0 + qrow0 + 16 + r16)*(size_t)DIM + h*HD;
    #pragma unroll
    for (int j=0;j<4;++j){
      bf16x4s ov;
      #pragma unroll
      for (int r=0;r<4;++r) ov[r] = f2bf(oaccB[j][r]*inv);
      *(bf16x4s*)&orow[j*16 + g*4] = ov;
    }
  }
}

extern "C" void kernel_launch(void* const* d_in, const int* in_sizes, int n_in,
                              void* d_out, int out_size, void* d_ws, size_t ws_size,
                              hipStream_t stream){
  const float* x  = (const float*)d_in[0];
  const float* wq = (const float*)d_in[1];
  const float* wk = (const float*)d_in[2];
  const float* wv = (const float*)d_in[3];
  const float* wo = (const float*)d_in[4];
  float* outf = (float*)d_out;   // FP32 output [4096, 2048]

  // Workspace (48.5 MB, time-shared):
  //   [0,16M):  wqkvb (12M, early) THEN attnb (16M, late)
  //   [16,24M): wob
  //   [24,48M): qkv
  //   [48,48.5M): cos/sin tables
  // d_out (32MB fp32) time-shared: [0,16M) xb bf16 (dead after QKV GEMM),
  //   [16,20M) Vtg bf16 V^T (dead before final GEMM writes d_out).
  char* ws = (char*)d_ws;
  short* wqkvb = (short*)(ws);
  short* attnb = (short*)(ws);
  short* wob   = (short*)(ws + 16777216);
  short* qkv   = (short*)(ws + 25165824);
  float* cosT  = (float*)(ws + 50331648);
  float* sinT  = (float*)(ws + 50593792);
  short* xb    = (short*)d_out;
  short* Vtg   = (short*)((char*)d_out + 16777216);

  cvt_all_kernel<<<18688, 256, 0, stream>>>(x, wq, wk, wv, wo, xb, wqkvb, wob, cosT, sinT);

  // QKV projection with fused RoPE (q/k) + V^T scatter (v): [4096,2048]x[3072,2048]^T
  gemm_bt_kernel<<<dim3(NQKV/128, MROWS/128), 256, 0, stream>>>(xb, wqkvb, qkv, Vtg,
                                                                NQKV, KDIM, cosT, sinT, 1);
  // attention (writes attnb, aliasing the now-dead wqkvb)
  attn_kernel<<<dim3(SS/256, NH, BB), 512, 0, stream>>>(qkv, Vtg, attnb);
  // O projection: [4096,2048] x [2048,2048]^T -> d_out as FP32
  gemm_btf_kernel<<<dim3(DIM/128, MROWS/128), 256, 0, stream>>>(attnb, wob, outf, DIM, KDIM);
}